// Round 3
// baseline (947.486 us; speedup 1.0000x reference)
//
#include <hip/hip_runtime.h>
#include <stdint.h>

#define FEAT 128
#define NNODES 512
#define BATCH 4
#define EDGES 97920              // sum_{r=257}^{511} r
#define BE (BATCH*EDGES)         // 391680
#define NSAMP 5
#define BASE_OFF 32896           // 256*257/2
#define CHUNKS 40                // gumbel blocks per (b,s)
#define NCOL (BATCH*NNODES)      // 2048 columns of PT/QT

// ---------------- threefry2x32 (exact JAX core, key=[0,42]) ------------------
__device__ __forceinline__ void threefry2x32(uint32_t k0, uint32_t k1,
                                             uint32_t& x0, uint32_t& x1) {
  uint32_t k2 = k0 ^ k1 ^ 0x1BD11BDAu;
  x0 += k0; x1 += k1;
#define RR(r) { x0 += x1; x1 = (x1 << (r)) | (x1 >> (32 - (r))); x1 ^= x0; }
  RR(13) RR(15) RR(26) RR(6)   x0 += k1; x1 += k2 + 1u;
  RR(17) RR(29) RR(16) RR(24)  x0 += k2; x1 += k0 + 2u;
  RR(13) RR(15) RR(26) RR(6)   x0 += k0; x1 += k1 + 3u;
  RR(17) RR(29) RR(16) RR(24)  x0 += k1; x1 += k2 + 4u;
  RR(13) RR(15) RR(26) RR(6)   x0 += k2; x1 += k0 + 5u;
#undef RR
}

// partitionable threefry gumbel (verified passing in round 2) — do not change
__device__ __forceinline__ double gumbel_val(uint32_t n) {
  uint32_t x0 = 0u, x1 = n;
  threefry2x32(0u, 42u, x0, x1);
  uint32_t bits = x0 ^ x1;
  uint32_t fb = (bits >> 9) | 0x3f800000u;
  float f = __uint_as_float(fb) - 1.0f;
  float u = fmaxf(f, 1.1754943508222875e-38f);
  return -log(-log((double)u));
}

__device__ __forceinline__ void fma4(float4& d, float s, const float4& v) {
  d.x = fmaf(s, v.x, d.x); d.y = fmaf(s, v.y, d.y);
  d.z = fmaf(s, v.z, d.z); d.w = fmaf(s, v.w, d.w);
}

// ---------------- kernel A: PT = (nodes @ W1_top + b1)^T, QT = (nodes @ W1_bot)^T
__global__ __launch_bounds__(256) void pq_kernel(
    const float* __restrict__ nodes, const float* __restrict__ W1,
    const float* __restrict__ b1, float* __restrict__ PT, float* __restrict__ QT) {
  __shared__ float snode[8][FEAT];
  const int row0 = blockIdx.x * 8;            // (b*512+n) rows, 8 per block
  const int tid = threadIdx.x;
  for (int i = tid; i < 8 * FEAT; i += 256)
    snode[i >> 7][i & 127] = nodes[row0 * FEAT + i];
  __syncthreads();
  const int j = tid & 127;
  const int half = tid >> 7;                   // 0 -> PT, 1 -> QT
  const float* w = W1 + half * FEAT * FEAT + j;
  float acc[8] = {0, 0, 0, 0, 0, 0, 0, 0};
  for (int k = 0; k < FEAT; ++k) {
    float wv = w[k * FEAT];
#pragma unroll
    for (int m = 0; m < 8; ++m) acc[m] += snode[m][k] * wv;
  }
  const float bv = half ? 0.0f : b1[j];
  float* out = half ? QT : PT;
  float4 v0 = {acc[0] + bv, acc[1] + bv, acc[2] + bv, acc[3] + bv};
  float4 v1 = {acc[4] + bv, acc[5] + bv, acc[6] + bv, acc[7] + bv};
  *(float4*)(out + j * NCOL + row0) = v0;
  *(float4*)(out + j * NCOL + row0 + 4) = v1;
}

// ---------------- edge index -> (sink, src) ----------------------------------
__global__ __launch_bounds__(256) void map_kernel(int2* __restrict__ map) {
  int e = blockIdx.x * blockDim.x + threadIdx.x;
  if (e >= EDGES) return;
  double x = (double)(e + BASE_OFF);
  int s = (int)((1.0 + sqrt(1.0 + 8.0 * x)) * 0.5);
  while ((long long)s * (s - 1) / 2 - BASE_OFF > e) --s;
  while ((long long)(s + 1) * s / 2 - BASE_OFF <= e) ++s;
  int src = e - (int)((long long)s * (s - 1) / 2 - BASE_OFF);
  map[e] = make_int2(s, src);
}

// ---------------- prep: G = g1*W2, SG, SB, GW3, scalars ----------------------
__global__ __launch_bounds__(256) void prep_kernel(
    const float* __restrict__ W2, const float* __restrict__ g1,
    const float* __restrict__ be1, const float* __restrict__ b2,
    const float* __restrict__ g2, const float* __restrict__ be2,
    const float* __restrict__ W3, const float* __restrict__ b3,
    float* __restrict__ G, float* __restrict__ SG, float* __restrict__ SB,
    float* __restrict__ GW3, float* __restrict__ SC) {
  const int tid = threadIdx.x;
  for (int idx = tid; idx < FEAT * FEAT; idx += 256)
    G[idx] = g1[idx >> 7] * W2[idx];
  if (tid < FEAT) {
    float sg = 0.f, sb = 0.f;
    for (int k = 0; k < FEAT; ++k) {
      float w = W2[k * FEAT + tid];
      sg = fmaf(g1[k], w, sg);
      sb = fmaf(be1[k], w, sb);
    }
    SG[tid] = sg;
    SB[tid] = sb + b2[tid];
    GW3[tid] = g2[tid] * W3[tid];
  }
  __syncthreads();
  if (tid == 0) {
    float a = 0.f, c = 0.f;
    for (int n = 0; n < FEAT; ++n) { a += GW3[n]; c = fmaf(be2[n], W3[n], c); }
    SC[0] = a; SC[1] = c + b3[0];
  }
}

// ---------------- main MLP kernel ---------------------------------------------
// Per wave: 32 edges. Stage 1 (lane=edge over transposed PT/QT) -> h into
// per-wave LDS [128k][32m]. Stage 2: 8m x 8n register-tiled fp32 GEMM,
// B-operand (g1-folded W2) streamed from L1/L2. LN1/LN2 folded algebraically.
__global__ __launch_bounds__(256, 2) void mlp_kernel(
    const float* __restrict__ PT, const float* __restrict__ QT,
    const int2* __restrict__ map, const float* __restrict__ G,
    const float* __restrict__ SG, const float* __restrict__ SB,
    const float* __restrict__ GW3, const float* __restrict__ SC,
    float* __restrict__ logits) {
  __shared__ float sx[4][4096];   // per-wave [128][32], 16 KB each, 64 KB total
  const int tid = threadIdx.x;
  const int lane = tid & 63;
  const int wave = tid >> 6;
  const int nl = lane & 15;       // n-lane: n = {4nl..4nl+3} U {64+4nl..+3}
  const int mg = lane >> 4;       // m-group: m = {4mg..4mg+3} U {16+4mg..+3}
  const int em = lane & 31;       // stage-1 edge index in tile
  const int p = lane >> 5;        // stage-1 k-parity

  const float4* SGv = (const float4*)SG;
  const float4* SBv = (const float4*)SB;
  const float4* GWv = (const float4*)GW3;
  const float4 sgA = SGv[nl], sgB = SGv[nl + 16];
  const float4 sbA = SBv[nl], sbB = SBv[nl + 16];
  const float4 gwA = GWv[nl], gwB = GWv[nl + 16];
  const float sgw3 = SC[0], cb = SC[1];

  const float4* w2v = (const float4*)G;       // [k][32 float4]
  float* sxw = sx[wave];
  const float4* sxv = (const float4*)sxw;     // [k][8 float4]

  const int ntiles = BE / 128;    // 3060, exact; tiles never cross batch
  for (int tile = blockIdx.x; tile < ntiles; tile += gridDim.x) {
    const int g0 = tile * 128 + wave * 32;
    const int b = g0 / EDGES;
    const int e0 = g0 - b * EDGES;
    const int bofs = b << 9;

    // ---- stage 1: h[k] = relu(PT[k][sink] + QT[k][src]); lane = (edge, k-parity)
    int2 ss = map[e0 + em];
    const float* pp = PT + p * NCOL + bofs + ss.x;
    const float* qq = QT + p * NCOL + bofs + ss.y;
    float s1 = 0.f, q1 = 0.f;
    float* srow = sxw + p * 32 + em;
#pragma unroll 16
    for (int k2 = 0; k2 < 64; ++k2) {
      float h = fmaxf(pp[k2 * 2 * NCOL] + qq[k2 * 2 * NCOL], 0.0f);
      s1 += h;
      q1 = fmaf(h, h, q1);
      srow[k2 * 64] = h;
    }
    s1 += __shfl_xor(s1, 32, 64);
    q1 += __shfl_xor(q1, 32, 64);
    const float mu1 = s1 * (1.0f / 128.0f);
    const float rstd1 = rsqrtf(fmaxf(q1 * (1.0f / 128.0f) - mu1 * mu1, 0.0f) + 1e-5f);

    // ---- stage 2: S_h[m][n] = sum_k h[k][m] * G[k][n], 8m x 8n per lane ----
    float4 acc[2][4][2];
#pragma unroll
    for (int a = 0; a < 2; ++a)
#pragma unroll
      for (int i = 0; i < 4; ++i)
#pragma unroll
        for (int c = 0; c < 2; ++c) acc[a][i][c] = make_float4(0.f, 0.f, 0.f, 0.f);

    float4 aA[2], aB[2], bA[2], bB[2];
    aA[0] = sxv[mg];      aB[0] = sxv[4 + mg];
    bA[0] = w2v[nl];      bB[0] = w2v[16 + nl];
#pragma unroll 2
    for (int k = 0; k < 128; ++k) {
      const int cur = k & 1, nxt = cur ^ 1;
      if (k < 127) {
        aA[nxt] = sxv[(k + 1) * 8 + mg];
        aB[nxt] = sxv[(k + 1) * 8 + 4 + mg];
        bA[nxt] = w2v[(k + 1) * 32 + nl];
        bB[nxt] = w2v[(k + 1) * 32 + 16 + nl];
      }
      const float4 a0 = aA[cur], a1 = aB[cur];
      const float4 b0 = bA[cur], b1v = bB[cur];
#pragma unroll
      for (int i = 0; i < 4; ++i) {
        const float amA = ((const float*)&a0)[i];
        const float amB = ((const float*)&a1)[i];
        fma4(acc[0][i][0], amA, b0); fma4(acc[0][i][1], amA, b1v);
        fma4(acc[1][i][0], amB, b0); fma4(acc[1][i][1], amB, b1v);
      }
    }

    // ---- epilogue: z = rstd1*(S_h - mu1*SG) + SB; h2=relu(z); LN2+W3 folded --
#pragma unroll
    for (int a = 0; a < 2; ++a)
#pragma unroll
      for (int i = 0; i < 4; ++i) {
        const int me = a * 16 + 4 * mg + i;
        const float mu_e = __shfl(mu1, me, 64);
        const float rs_e = __shfl(rstd1, me, 64);
        float h2[8];
        {
          const float4 cA = acc[a][i][0], cB = acc[a][i][1];
          h2[0] = fmaxf(rs_e * (cA.x - mu_e * sgA.x) + sbA.x, 0.f);
          h2[1] = fmaxf(rs_e * (cA.y - mu_e * sgA.y) + sbA.y, 0.f);
          h2[2] = fmaxf(rs_e * (cA.z - mu_e * sgA.z) + sbA.z, 0.f);
          h2[3] = fmaxf(rs_e * (cA.w - mu_e * sgA.w) + sbA.w, 0.f);
          h2[4] = fmaxf(rs_e * (cB.x - mu_e * sgB.x) + sbB.x, 0.f);
          h2[5] = fmaxf(rs_e * (cB.y - mu_e * sgB.y) + sbB.y, 0.f);
          h2[6] = fmaxf(rs_e * (cB.z - mu_e * sgB.z) + sbB.z, 0.f);
          h2[7] = fmaxf(rs_e * (cB.w - mu_e * sgB.w) + sbB.w, 0.f);
        }
        float s2 = 0.f, q2 = 0.f, t = 0.f;
        const float* gwa = (const float*)&gwA;
        const float* gwb = (const float*)&gwB;
#pragma unroll
        for (int j = 0; j < 4; ++j) {
          s2 += h2[j] + h2[4 + j];
          q2 = fmaf(h2[j], h2[j], q2); q2 = fmaf(h2[4 + j], h2[4 + j], q2);
          t = fmaf(h2[j], gwa[j], t);  t = fmaf(h2[4 + j], gwb[j], t);
        }
#pragma unroll
        for (int off = 1; off < 16; off <<= 1) {
          s2 += __shfl_xor(s2, off, 64);
          q2 += __shfl_xor(q2, off, 64);
          t  += __shfl_xor(t,  off, 64);
        }
        const float mu2 = s2 * (1.0f / 128.0f);
        const float var2 = fmaxf(q2 * (1.0f / 128.0f) - mu2 * mu2, 0.0f);
        const float rs2 = rsqrtf(var2 + 1e-5f);
        const float lg = rs2 * (t - mu2 * sgw3) + cb;
        if (nl == 0) logits[g0 + me] = lg;
      }
  }
}

// ---------------- gumbel argmax, stage 1: per-(bs,chunk) best ----------------
__global__ __launch_bounds__(256) void gumbel_kernel(
    const float* __restrict__ logits, double* __restrict__ bestval,
    int* __restrict__ bestidx) {
  const int bs = blockIdx.x / CHUNKS;     // b*5 + s
  const int chunk = blockIdx.x % CHUNKS;
  const int b = bs / NSAMP;
  const float* lg = logits + b * EDGES;
  double best = -1e300; int bi = 0x7fffffff;
  for (int e = chunk * 256 + threadIdx.x; e < EDGES; e += CHUNKS * 256) {
    uint32_t n = (uint32_t)(bs * EDGES + e);
    double val = (double)lg[e] + gumbel_val(n);
    if (val > best) { best = val; bi = e; }
  }
  __shared__ double sv[256];
  __shared__ int si[256];
  sv[threadIdx.x] = best; si[threadIdx.x] = bi;
  __syncthreads();
  for (int off = 128; off; off >>= 1) {
    if (threadIdx.x < off) {
      double ov = sv[threadIdx.x + off]; int oi = si[threadIdx.x + off];
      if (ov > sv[threadIdx.x] ||
          (ov == sv[threadIdx.x] && oi < si[threadIdx.x])) {
        sv[threadIdx.x] = ov; si[threadIdx.x] = oi;
      }
    }
    __syncthreads();
  }
  if (threadIdx.x == 0) { bestval[blockIdx.x] = sv[0]; bestidx[blockIdx.x] = si[0]; }
}

// ---------------- gumbel argmax, stage 2: winner -> adj ----------------------
__global__ __launch_bounds__(64) void select_kernel(
    const double* __restrict__ bestval, const int* __restrict__ bestidx,
    const int2* __restrict__ map, float* __restrict__ adj) {
  const int bs = blockIdx.x;
  const int lane = threadIdx.x;
  double v = -1e300; int idx = 0x7fffffff;
  if (lane < CHUNKS) { v = bestval[bs * CHUNKS + lane]; idx = bestidx[bs * CHUNKS + lane]; }
#pragma unroll
  for (int off = 32; off; off >>= 1) {
    double ov = __shfl_xor(v, off, 64);
    int oi = __shfl_xor(idx, off, 64);
    if (ov > v || (ov == v && oi < idx)) { v = ov; idx = oi; }
  }
  if (lane == 0) {
    int b = bs / NSAMP;
    int2 ss = map[idx];
    adj[((b * NNODES) + ss.x) * NNODES + ss.y] = 1.0f;
  }
}

extern "C" void kernel_launch(void* const* d_in, const int* in_sizes, int n_in,
                              void* d_out, int out_size, void* d_ws, size_t ws_size,
                              hipStream_t stream) {
  const float* nodes = (const float*)d_in[0];
  const float* W1  = (const float*)d_in[1];
  const float* b1  = (const float*)d_in[2];
  const float* g1  = (const float*)d_in[3];
  const float* be1 = (const float*)d_in[4];
  const float* W2  = (const float*)d_in[5];
  const float* b2  = (const float*)d_in[6];
  const float* g2  = (const float*)d_in[7];
  const float* be2 = (const float*)d_in[8];
  const float* W3  = (const float*)d_in[9];
  const float* b3  = (const float*)d_in[10];
  float* adj = (float*)d_out;

  char* ws = (char*)d_ws;
  float* PT      = (float*)(ws);                       // 1 MB  [128][2048]
  float* QT      = (float*)(ws + (1 << 20));           // 1 MB
  int2*  map     = (int2*) (ws + (2 << 20));           // 783 KB
  float* logits  = (float*)(ws + (3 << 20));           // 1.57 MB
  float* G       = (float*)(ws + (5 << 20));           // 64 KB
  float* SG      = (float*)(ws + (5 << 20) + 65536);
  float* SB      = (float*)(ws + (5 << 20) + 66048);
  float* GW3     = (float*)(ws + (5 << 20) + 66560);
  float* SC      = (float*)(ws + (5 << 20) + 67072);
  double* bestval = (double*)(ws + (5 << 20) + 131072);  // 800*8
  int*    bestidx = (int*)   (ws + (5 << 20) + 137472);  // 800*4

  hipMemsetAsync(adj, 0, (size_t)out_size * sizeof(float), stream);
  pq_kernel<<<(BATCH * NNODES) / 8, 256, 0, stream>>>(nodes, W1, b1, PT, QT);
  map_kernel<<<(EDGES + 255) / 256, 256, 0, stream>>>(map);
  prep_kernel<<<1, 256, 0, stream>>>(W2, g1, be1, b2, g2, be2, W3, b3,
                                     G, SG, SB, GW3, SC);
  mlp_kernel<<<512, 256, 0, stream>>>(PT, QT, map, G, SG, SB, GW3, SC, logits);
  gumbel_kernel<<<20 * CHUNKS, 256, 0, stream>>>(logits, bestval, bestidx);
  select_kernel<<<20, 64, 0, stream>>>(bestval, bestidx, map, adj);
}

// Round 4
// 524.899 us; speedup vs baseline: 1.8051x; 1.8051x over previous
//
#include <hip/hip_runtime.h>
#include <stdint.h>

#define FEAT 128
#define NNODES 512
#define BATCH 4
#define EDGES 97920              // sum_{r=257}^{511} r
#define BE (BATCH*EDGES)         // 391680
#define NSAMP 5
#define BASE_OFF 32896           // 256*257/2
#define CHUNKS 40                // gumbel blocks per (b,s)
#define EPW 24                   // edges per wave-tile
#define XSTRIDE 25               // LDS x stride (col 24 spare for stats)
#define NWT (BE/EPW)             // 16320 wave-tiles

// ---------------- threefry2x32 (exact JAX core, key=[0,42]) ------------------
__device__ __forceinline__ void threefry2x32(uint32_t k0, uint32_t k1,
                                             uint32_t& x0, uint32_t& x1) {
  uint32_t k2 = k0 ^ k1 ^ 0x1BD11BDAu;
  x0 += k0; x1 += k1;
#define RR(r) { x0 += x1; x1 = (x1 << (r)) | (x1 >> (32 - (r))); x1 ^= x0; }
  RR(13) RR(15) RR(26) RR(6)   x0 += k1; x1 += k2 + 1u;
  RR(17) RR(29) RR(16) RR(24)  x0 += k2; x1 += k0 + 2u;
  RR(13) RR(15) RR(26) RR(6)   x0 += k0; x1 += k1 + 3u;
  RR(17) RR(29) RR(16) RR(24)  x0 += k1; x1 += k2 + 4u;
  RR(13) RR(15) RR(26) RR(6)   x0 += k2; x1 += k0 + 5u;
#undef RR
}

// partitionable threefry gumbel (verified passing rounds 2-3) — do not change
__device__ __forceinline__ double gumbel_val(uint32_t n) {
  uint32_t x0 = 0u, x1 = n;
  threefry2x32(0u, 42u, x0, x1);
  uint32_t bits = x0 ^ x1;
  uint32_t fb = (bits >> 9) | 0x3f800000u;
  float f = __uint_as_float(fb) - 1.0f;
  float u = fmaxf(f, 1.1754943508222875e-38f);
  return -log(-log((double)u));
}

__device__ __forceinline__ void fma4(float4& d, float s, const float4& v) {
  d.x = fmaf(s, v.x, d.x); d.y = fmaf(s, v.y, d.y);
  d.z = fmaf(s, v.z, d.z); d.w = fmaf(s, v.w, d.w);
}

// ---------------- kernel A: P = nodes @ W1_top + b1, Q = nodes @ W1_bot ------
// Row-major [2048][128] (round-2 layout: stage-1 loads are coalesced float2).
__global__ __launch_bounds__(256) void pq_kernel(
    const float* __restrict__ nodes, const float* __restrict__ W1,
    const float* __restrict__ b1, float* __restrict__ P, float* __restrict__ Q) {
  __shared__ float snode[8][FEAT];
  const int row0 = blockIdx.x * 8;
  const int tid = threadIdx.x;
  for (int i = tid; i < 8 * FEAT; i += 256)
    snode[i >> 7][i & 127] = nodes[row0 * FEAT + i];
  __syncthreads();
  const int j = tid & 127;
  const int half = tid >> 7;                   // 0 -> P, 1 -> Q
  const float* w = W1 + half * FEAT * FEAT + j;
  float acc[8] = {0, 0, 0, 0, 0, 0, 0, 0};
  for (int k = 0; k < FEAT; ++k) {
    float wv = w[k * FEAT];
#pragma unroll
    for (int m = 0; m < 8; ++m) acc[m] += snode[m][k] * wv;
  }
  const float bv = half ? 0.0f : b1[j];
  float* out = half ? Q : P;
#pragma unroll
  for (int m = 0; m < 8; ++m) out[(row0 + m) * FEAT + j] = acc[m] + bv;
}

// ---------------- edge index -> (sink, src) ----------------------------------
__global__ __launch_bounds__(256) void map_kernel(int2* __restrict__ map) {
  int e = blockIdx.x * blockDim.x + threadIdx.x;
  if (e >= EDGES) return;
  double x = (double)(e + BASE_OFF);
  int s = (int)((1.0 + sqrt(1.0 + 8.0 * x)) * 0.5);
  while ((long long)s * (s - 1) / 2 - BASE_OFF > e) --s;
  while ((long long)(s + 1) * s / 2 - BASE_OFF <= e) ++s;
  int src = e - (int)((long long)s * (s - 1) / 2 - BASE_OFF);
  map[e] = make_int2(s, src);
}

// ---------------- prep: G = g1*W2, SG, SB, GW3, scalars (verified round 3) ---
__global__ __launch_bounds__(256) void prep_kernel(
    const float* __restrict__ W2, const float* __restrict__ g1,
    const float* __restrict__ be1, const float* __restrict__ b2,
    const float* __restrict__ g2, const float* __restrict__ be2,
    const float* __restrict__ W3, const float* __restrict__ b3,
    float* __restrict__ G, float* __restrict__ SG, float* __restrict__ SB,
    float* __restrict__ GW3, float* __restrict__ SC) {
  const int tid = threadIdx.x;
  for (int idx = tid; idx < FEAT * FEAT; idx += 256)
    G[idx] = g1[idx >> 7] * W2[idx];
  if (tid < FEAT) {
    float sg = 0.f, sb = 0.f;
    for (int k = 0; k < FEAT; ++k) {
      float w = W2[k * FEAT + tid];
      sg = fmaf(g1[k], w, sg);
      sb = fmaf(be1[k], w, sb);
    }
    SG[tid] = sg;
    SB[tid] = sb + b2[tid];
    GW3[tid] = g2[tid] * W3[tid];
  }
  __syncthreads();
  if (tid == 0) {
    float a = 0.f, c = 0.f;
    for (int n = 0; n < FEAT; ++n) { a += GW3[n]; c = fmaf(be2[n], W3[n], c); }
    SC[0] = a; SC[1] = c + b3[0];
  }
}

// ---------------- main MLP kernel ---------------------------------------------
// Per wave: 24 edges, no block-level sync in the tile loop.
// Stage 1: coalesced float2 P/Q loads (lane = feature pair), h -> LDS [128][25].
// Stats: column re-read (conflict-free), mu/rstd stored in spare col 24.
// Stage 2: 6m x 8n register tile; A from LDS (3x ds_read_b64, 16-lane bcast),
// B = g1-folded W2 from global L1/L2 (2x b128, depth-2 pipeline).
__global__ __launch_bounds__(256, 3) void mlp_kernel(
    const float* __restrict__ P, const float* __restrict__ Q,
    const int2* __restrict__ map, const float* __restrict__ G,
    const float* __restrict__ SG, const float* __restrict__ SB,
    const float* __restrict__ GW3, const float* __restrict__ SC,
    float* __restrict__ logits) {
  __shared__ float sx[4][128 * XSTRIDE];   // 4 x 12.8 KB = 51.2 KB
  const int tid = threadIdx.x;
  const int lane = tid & 63;
  const int wave = tid >> 6;
  const int l2 = lane * 2;
  const int nl = lane & 15;       // n = {4nl..4nl+3} U {64+4nl..+3}
  const int mg = lane >> 4;       // m = {6mg..6mg+5}

  const float4* SGv = (const float4*)SG;
  const float4* SBv = (const float4*)SB;
  const float4* GWv = (const float4*)GW3;
  const float4 sgA = SGv[nl], sgB = SGv[nl + 16];
  const float4 sbA = SBv[nl], sbB = SBv[nl + 16];
  const float4 gwA = GWv[nl], gwB = GWv[nl + 16];
  const float sgw3 = SC[0], cb = SC[1];

  float* sxw = sx[wave];
  const float* gk = G + 4 * nl;

  for (int wt = blockIdx.x * 4 + wave; wt < NWT; wt += gridDim.x * 4) {
    const int g0 = wt * EPW;
    const int b = g0 / EDGES;          // EPW | EDGES: tile never crosses batch
    const int e0 = g0 - b * EDGES;
    const float* Pb = P + ((size_t)(b << 9) << 7);
    const float* Qb = Q + ((size_t)(b << 9) << 7);

    // ---- stage 1: h = relu(P[sink] + Q[src]) -> sx[k][m], coalesced loads ----
#pragma unroll 8
    for (int m = 0; m < EPW; ++m) {
      int2 ss = map[e0 + m];
      float2 pv = *(const float2*)(Pb + (ss.x << 7) + l2);
      float2 qv = *(const float2*)(Qb + (ss.y << 7) + l2);
      sxw[l2 * XSTRIDE + m] = fmaxf(pv.x + qv.x, 0.0f);
      sxw[(l2 + 1) * XSTRIDE + m] = fmaxf(pv.y + qv.y, 0.0f);
    }
    __builtin_amdgcn_wave_barrier();

    // ---- LN1 stats via column read; store mu/rstd in spare col 24 ----
    if (lane < EPW) {
      float s1 = 0.f, q1 = 0.f;
      const float* col = sxw + lane;
#pragma unroll 16
      for (int k = 0; k < 128; ++k) {
        float h = col[k * XSTRIDE];
        s1 += h;
        q1 = fmaf(h, h, q1);
      }
      const float mu = s1 * (1.0f / 128.0f);
      const float var = fmaxf(q1 * (1.0f / 128.0f) - mu * mu, 0.0f);
      sxw[lane * XSTRIDE + 24] = mu;
      sxw[(64 + lane) * XSTRIDE + 24] = rsqrtf(var + 1e-5f);
    }
    __builtin_amdgcn_wave_barrier();

    // ---- stage 2: S_h[m][n] = sum_k h[k][m] * G[k][n], 6m x 8n per lane ----
    float4 acc[6][2];
#pragma unroll
    for (int i = 0; i < 6; ++i) {
      acc[i][0] = make_float4(0.f, 0.f, 0.f, 0.f);
      acc[i][1] = make_float4(0.f, 0.f, 0.f, 0.f);
    }

    float2 aa[2][3];
    float4 vbA[2], vbB[2];
    const float* arow = sxw + 6 * mg;
#pragma unroll
    for (int j = 0; j < 3; ++j) {
      aa[0][j] = *(const float2*)(arow + 2 * j);
      aa[1][j] = *(const float2*)(arow + XSTRIDE + 2 * j);
    }
    vbA[0] = *(const float4*)(gk);        vbB[0] = *(const float4*)(gk + 64);
    vbA[1] = *(const float4*)(gk + 128);  vbB[1] = *(const float4*)(gk + 192);

#pragma unroll 2
    for (int k = 0; k < 128; ++k) {
      const int cur = k & 1;
      const float4 cbA = vbA[cur], cbB = vbB[cur];
      const float a0 = aa[cur][0].x, a1 = aa[cur][0].y;
      const float a2 = aa[cur][1].x, a3 = aa[cur][1].y;
      const float a4 = aa[cur][2].x, a5 = aa[cur][2].y;
      if (k < 126) {
        const float* arow2 = arow + (k + 2) * XSTRIDE;
#pragma unroll
        for (int j = 0; j < 3; ++j) aa[cur][j] = *(const float2*)(arow2 + 2 * j);
        vbA[cur] = *(const float4*)(gk + (k + 2) * 128);
        vbB[cur] = *(const float4*)(gk + (k + 2) * 128 + 64);
      }
      fma4(acc[0][0], a0, cbA); fma4(acc[0][1], a0, cbB);
      fma4(acc[1][0], a1, cbA); fma4(acc[1][1], a1, cbB);
      fma4(acc[2][0], a2, cbA); fma4(acc[2][1], a2, cbB);
      fma4(acc[3][0], a3, cbA); fma4(acc[3][1], a3, cbB);
      fma4(acc[4][0], a4, cbA); fma4(acc[4][1], a4, cbB);
      fma4(acc[5][0], a5, cbA); fma4(acc[5][1], a5, cbB);
    }

    // ---- epilogue (round-3 verified math): LN1 fold, relu, LN2+W3 fold ----
#pragma unroll
    for (int i = 0; i < 6; ++i) {
      const int me = 6 * mg + i;
      const float mu_e = sxw[me * XSTRIDE + 24];
      const float rs_e = sxw[(64 + me) * XSTRIDE + 24];
      float h2[8];
      {
        const float4 cA = acc[i][0], cB = acc[i][1];
        h2[0] = fmaxf(rs_e * (cA.x - mu_e * sgA.x) + sbA.x, 0.f);
        h2[1] = fmaxf(rs_e * (cA.y - mu_e * sgA.y) + sbA.y, 0.f);
        h2[2] = fmaxf(rs_e * (cA.z - mu_e * sgA.z) + sbA.z, 0.f);
        h2[3] = fmaxf(rs_e * (cA.w - mu_e * sgA.w) + sbA.w, 0.f);
        h2[4] = fmaxf(rs_e * (cB.x - mu_e * sgB.x) + sbB.x, 0.f);
        h2[5] = fmaxf(rs_e * (cB.y - mu_e * sgB.y) + sbB.y, 0.f);
        h2[6] = fmaxf(rs_e * (cB.z - mu_e * sgB.z) + sbB.z, 0.f);
        h2[7] = fmaxf(rs_e * (cB.w - mu_e * sgB.w) + sbB.w, 0.f);
      }
      float s2 = 0.f, q2 = 0.f, t = 0.f;
      const float* gwa = (const float*)&gwA;
      const float* gwb = (const float*)&gwB;
#pragma unroll
      for (int j = 0; j < 4; ++j) {
        s2 += h2[j] + h2[4 + j];
        q2 = fmaf(h2[j], h2[j], q2); q2 = fmaf(h2[4 + j], h2[4 + j], q2);
        t = fmaf(h2[j], gwa[j], t);  t = fmaf(h2[4 + j], gwb[j], t);
      }
#pragma unroll
      for (int off = 1; off < 16; off <<= 1) {
        s2 += __shfl_xor(s2, off, 64);
        q2 += __shfl_xor(q2, off, 64);
        t  += __shfl_xor(t,  off, 64);
      }
      const float mu2 = s2 * (1.0f / 128.0f);
      const float var2 = fmaxf(q2 * (1.0f / 128.0f) - mu2 * mu2, 0.0f);
      const float rs2 = rsqrtf(var2 + 1e-5f);
      if (nl == 0) logits[g0 + me] = rs2 * (t - mu2 * sgw3) + cb;
    }
    __builtin_amdgcn_wave_barrier();
  }
}

// ---------------- gumbel argmax, stage 1: per-(bs,chunk) best ----------------
__global__ __launch_bounds__(256) void gumbel_kernel(
    const float* __restrict__ logits, double* __restrict__ bestval,
    int* __restrict__ bestidx) {
  const int bs = blockIdx.x / CHUNKS;     // b*5 + s
  const int chunk = blockIdx.x % CHUNKS;
  const int b = bs / NSAMP;
  const float* lg = logits + b * EDGES;
  double best = -1e300; int bi = 0x7fffffff;
  for (int e = chunk * 256 + threadIdx.x; e < EDGES; e += CHUNKS * 256) {
    uint32_t n = (uint32_t)(bs * EDGES + e);
    double val = (double)lg[e] + gumbel_val(n);
    if (val > best) { best = val; bi = e; }
  }
  __shared__ double sv[256];
  __shared__ int si[256];
  sv[threadIdx.x] = best; si[threadIdx.x] = bi;
  __syncthreads();
  for (int off = 128; off; off >>= 1) {
    if (threadIdx.x < off) {
      double ov = sv[threadIdx.x + off]; int oi = si[threadIdx.x + off];
      if (ov > sv[threadIdx.x] ||
          (ov == sv[threadIdx.x] && oi < si[threadIdx.x])) {
        sv[threadIdx.x] = ov; si[threadIdx.x] = oi;
      }
    }
    __syncthreads();
  }
  if (threadIdx.x == 0) { bestval[blockIdx.x] = sv[0]; bestidx[blockIdx.x] = si[0]; }
}

// ---------------- gumbel argmax, stage 2: winner -> adj ----------------------
__global__ __launch_bounds__(64) void select_kernel(
    const double* __restrict__ bestval, const int* __restrict__ bestidx,
    const int2* __restrict__ map, float* __restrict__ adj) {
  const int bs = blockIdx.x;
  const int lane = threadIdx.x;
  double v = -1e300; int idx = 0x7fffffff;
  if (lane < CHUNKS) { v = bestval[bs * CHUNKS + lane]; idx = bestidx[bs * CHUNKS + lane]; }
#pragma unroll
  for (int off = 32; off; off >>= 1) {
    double ov = __shfl_xor(v, off, 64);
    int oi = __shfl_xor(idx, off, 64);
    if (ov > v || (ov == v && oi < idx)) { v = ov; idx = oi; }
  }
  if (lane == 0) {
    int b = bs / NSAMP;
    int2 ss = map[idx];
    adj[((b * NNODES) + ss.x) * NNODES + ss.y] = 1.0f;
  }
}

extern "C" void kernel_launch(void* const* d_in, const int* in_sizes, int n_in,
                              void* d_out, int out_size, void* d_ws, size_t ws_size,
                              hipStream_t stream) {
  const float* nodes = (const float*)d_in[0];
  const float* W1  = (const float*)d_in[1];
  const float* b1  = (const float*)d_in[2];
  const float* g1  = (const float*)d_in[3];
  const float* be1 = (const float*)d_in[4];
  const float* W2  = (const float*)d_in[5];
  const float* b2  = (const float*)d_in[6];
  const float* g2  = (const float*)d_in[7];
  const float* be2 = (const float*)d_in[8];
  const float* W3  = (const float*)d_in[9];
  const float* b3  = (const float*)d_in[10];
  float* adj = (float*)d_out;

  char* ws = (char*)d_ws;
  float* P       = (float*)(ws);                       // 1 MB  [2048][128]
  float* Q       = (float*)(ws + (1 << 20));           // 1 MB
  int2*  map     = (int2*) (ws + (2 << 20));           // 783 KB
  float* logits  = (float*)(ws + (3 << 20));           // 1.57 MB
  float* G       = (float*)(ws + (5 << 20));           // 64 KB
  float* SG      = (float*)(ws + (5 << 20) + 65536);
  float* SB      = (float*)(ws + (5 << 20) + 66048);
  float* GW3     = (float*)(ws + (5 << 20) + 66560);
  float* SC      = (float*)(ws + (5 << 20) + 67072);
  double* bestval = (double*)(ws + (5 << 20) + 131072);  // 800*8
  int*    bestidx = (int*)   (ws + (5 << 20) + 137472);  // 800*4

  hipMemsetAsync(adj, 0, (size_t)out_size * sizeof(float), stream);
  pq_kernel<<<(BATCH * NNODES) / 8, 256, 0, stream>>>(nodes, W1, b1, P, Q);
  map_kernel<<<(EDGES + 255) / 256, 256, 0, stream>>>(map);
  prep_kernel<<<1, 256, 0, stream>>>(W2, g1, be1, b2, g2, be2, W3, b3,
                                     G, SG, SB, GW3, SC);
  mlp_kernel<<<768, 256, 0, stream>>>(P, Q, map, G, SG, SB, GW3, SC, logits);
  gumbel_kernel<<<20 * CHUNKS, 256, 0, stream>>>(logits, bestval, bestidx);
  select_kernel<<<20, 64, 0, stream>>>(bestval, bestidx, map, adj);
}

// Round 5
// 477.588 us; speedup vs baseline: 1.9839x; 1.0991x over previous
//
#include <hip/hip_runtime.h>
#include <stdint.h>

#define FEAT 128
#define NNODES 512
#define BATCH 4
#define EDGES 97920              // sum_{r=257}^{511} r ; 64 | EDGES
#define BE (BATCH*EDGES)         // 391680
#define NSAMP 5
#define BASE_OFF 32896           // 256*257/2
#define CHUNKS 40                // gumbel blocks per (b,s)
#define NWT (BE/64)              // 6120 wave-tiles (64 edges per wave)

// ---------------- threefry2x32 (exact JAX core, key=[0,42]) ------------------
__device__ __forceinline__ void threefry2x32(uint32_t k0, uint32_t k1,
                                             uint32_t& x0, uint32_t& x1) {
  uint32_t k2 = k0 ^ k1 ^ 0x1BD11BDAu;
  x0 += k0; x1 += k1;
#define RR(r) { x0 += x1; x1 = (x1 << (r)) | (x1 >> (32 - (r))); x1 ^= x0; }
  RR(13) RR(15) RR(26) RR(6)   x0 += k1; x1 += k2 + 1u;
  RR(17) RR(29) RR(16) RR(24)  x0 += k2; x1 += k0 + 2u;
  RR(13) RR(15) RR(26) RR(6)   x0 += k0; x1 += k1 + 3u;
  RR(17) RR(29) RR(16) RR(24)  x0 += k1; x1 += k2 + 4u;
  RR(13) RR(15) RR(26) RR(6)   x0 += k2; x1 += k0 + 5u;
#undef RR
}

// partitionable threefry gumbel (verified passing rounds 2-4) — do not change
__device__ __forceinline__ double gumbel_val(uint32_t n) {
  uint32_t x0 = 0u, x1 = n;
  threefry2x32(0u, 42u, x0, x1);
  uint32_t bits = x0 ^ x1;
  uint32_t fb = (bits >> 9) | 0x3f800000u;
  float f = __uint_as_float(fb) - 1.0f;
  float u = fmaxf(f, 1.1754943508222875e-38f);
  return -log(-log((double)u));
}

// ---------------- kernel A: P = nodes @ W1_top + b1, Q = nodes @ W1_bot ------
__global__ __launch_bounds__(256) void pq_kernel(
    const float* __restrict__ nodes, const float* __restrict__ W1,
    const float* __restrict__ b1, float* __restrict__ P, float* __restrict__ Q) {
  __shared__ float snode[8][FEAT];
  const int row0 = blockIdx.x * 8;
  const int tid = threadIdx.x;
  for (int i = tid; i < 8 * FEAT; i += 256)
    snode[i >> 7][i & 127] = nodes[row0 * FEAT + i];
  __syncthreads();
  const int j = tid & 127;
  const int half = tid >> 7;                   // 0 -> P, 1 -> Q
  const float* w = W1 + half * FEAT * FEAT + j;
  float acc[8] = {0, 0, 0, 0, 0, 0, 0, 0};
  for (int k = 0; k < FEAT; ++k) {
    float wv = w[k * FEAT];
#pragma unroll
    for (int m = 0; m < 8; ++m) acc[m] += snode[m][k] * wv;
  }
  const float bv = half ? 0.0f : b1[j];
  float* out = half ? Q : P;
#pragma unroll
  for (int m = 0; m < 8; ++m) out[(row0 + m) * FEAT + j] = acc[m] + bv;
}

// ---------------- edge index -> (sink, src) ----------------------------------
__global__ __launch_bounds__(256) void map_kernel(int2* __restrict__ map) {
  int e = blockIdx.x * blockDim.x + threadIdx.x;
  if (e >= EDGES) return;
  double x = (double)(e + BASE_OFF);
  int s = (int)((1.0 + sqrt(1.0 + 8.0 * x)) * 0.5);
  while ((long long)s * (s - 1) / 2 - BASE_OFF > e) --s;
  while ((long long)(s + 1) * s / 2 - BASE_OFF <= e) ++s;
  int src = e - (int)((long long)s * (s - 1) / 2 - BASE_OFF);
  map[e] = make_int2(s, src);
}

// ---------------- prep: GT[n][k] = g1[k]*W2[k][n], SG, SB, GW3, SC -----------
__global__ __launch_bounds__(256) void prep_kernel(
    const float* __restrict__ W2, const float* __restrict__ g1,
    const float* __restrict__ be1, const float* __restrict__ b2,
    const float* __restrict__ g2, const float* __restrict__ be2,
    const float* __restrict__ W3, const float* __restrict__ b3,
    float* __restrict__ GT, float* __restrict__ SG, float* __restrict__ SB,
    float* __restrict__ GW3, float* __restrict__ SC) {
  const int tid = threadIdx.x;
  for (int idx = tid; idx < FEAT * FEAT; idx += 256) {
    const int n = idx >> 7, k = idx & 127;
    GT[idx] = g1[k] * W2[k * FEAT + n];
  }
  if (tid < FEAT) {
    float sg = 0.f, sb = 0.f;
    for (int k = 0; k < FEAT; ++k) {
      float w = W2[k * FEAT + tid];
      sg = fmaf(g1[k], w, sg);
      sb = fmaf(be1[k], w, sb);
    }
    SG[tid] = sg;
    SB[tid] = sb + b2[tid];
    GW3[tid] = g2[tid] * W3[tid];
  }
  __syncthreads();
  if (tid == 0) {
    float a = 0.f, c = 0.f;
    for (int n = 0; n < FEAT; ++n) { a += GW3[n]; c = fmaf(be2[n], W3[n], c); }
    SC[0] = a; SC[1] = c + b3[0];
  }
}

// ---------------- main MLP kernel ---------------------------------------------
// lane = edge. h[128] register-resident (32 float4). No LDS, no shuffles, no
// barriers. Stage-2 B operand (GT column, wave-uniform) via scalar loads ->
// v_fmac_f32 with SGPR source. LN1/LN2 folded per round-3 verified math.
__global__ __launch_bounds__(256, 3) void mlp_kernel(
    const float* __restrict__ P, const float* __restrict__ Q,
    const int2* __restrict__ map, const float* __restrict__ GT,
    const float* __restrict__ SG, const float* __restrict__ SB,
    const float* __restrict__ GW3, const float* __restrict__ SC,
    float* __restrict__ logits) {
  const int lane = threadIdx.x & 63;
  const int wave = (blockIdx.x << 2) + (threadIdx.x >> 6);
  const float sgw3 = SC[0], cb = SC[1];

  for (int wt = wave; wt < NWT; wt += gridDim.x * 4) {
    const int g0 = wt * 64;
    const int b = g0 / EDGES;            // 64 | EDGES: tile never crosses batch
    const int e = (g0 - b * EDGES) + lane;
    const int2 ss = map[e];
    const float4* prow = (const float4*)(P + (((b << 9) + ss.x) << 7));
    const float4* qrow = (const float4*)(Q + (((b << 9) + ss.y) << 7));

    // ---- stage 1: h = relu(P[sink] + Q[src]) into registers; LN1 stats ----
    float4 h4[32];
    float s1 = 0.f, q1 = 0.f;
#pragma unroll
    for (int i = 0; i < 32; ++i) {
      const float4 pv = prow[i];
      const float4 qv = qrow[i];
      float4 h;
      h.x = fmaxf(pv.x + qv.x, 0.f);
      h.y = fmaxf(pv.y + qv.y, 0.f);
      h.z = fmaxf(pv.z + qv.z, 0.f);
      h.w = fmaxf(pv.w + qv.w, 0.f);
      h4[i] = h;
      s1 += (h.x + h.y) + (h.z + h.w);
      q1 = fmaf(h.x, h.x, q1); q1 = fmaf(h.y, h.y, q1);
      q1 = fmaf(h.z, h.z, q1); q1 = fmaf(h.w, h.w, q1);
    }
    const float mu1 = s1 * (1.0f / 128.0f);
    const float var1 = fmaxf(q1 * (1.0f / 128.0f) - mu1 * mu1, 0.0f);
    const float rs1 = rsqrtf(var1 + 1e-5f);

    // ---- stage 2: per n, S = h . GT[n]; fold LN1; relu; LN2 stats ----
    float s2 = 0.f, q2 = 0.f, t = 0.f;
    for (int n = 0; n < FEAT; ++n) {
      const float* gc = GT + (n << 7);        // wave-uniform -> s_load
      float a0 = 0.f, a1 = 0.f, a2 = 0.f, a3 = 0.f;
#pragma unroll
      for (int i = 0; i < 32; ++i) {
        a0 = fmaf(h4[i].x, gc[4 * i + 0], a0);
        a1 = fmaf(h4[i].y, gc[4 * i + 1], a1);
        a2 = fmaf(h4[i].z, gc[4 * i + 2], a2);
        a3 = fmaf(h4[i].w, gc[4 * i + 3], a3);
      }
      const float S = (a0 + a1) + (a2 + a3);
      const float h2 = fmaxf(rs1 * (S - mu1 * SG[n]) + SB[n], 0.f);
      s2 += h2;
      q2 = fmaf(h2, h2, q2);
      t = fmaf(h2, GW3[n], t);
    }
    const float mu2 = s2 * (1.0f / 128.0f);
    const float var2 = fmaxf(q2 * (1.0f / 128.0f) - mu2 * mu2, 0.0f);
    const float rs2 = rsqrtf(var2 + 1e-5f);
    logits[g0 + lane] = rs2 * (t - mu2 * sgw3) + cb;
  }
}

// ---------------- gumbel argmax, stage 1: per-(bs,chunk) best ----------------
__global__ __launch_bounds__(256) void gumbel_kernel(
    const float* __restrict__ logits, double* __restrict__ bestval,
    int* __restrict__ bestidx) {
  const int bs = blockIdx.x / CHUNKS;     // b*5 + s
  const int chunk = blockIdx.x % CHUNKS;
  const int b = bs / NSAMP;
  const float* lg = logits + b * EDGES;
  double best = -1e300; int bi = 0x7fffffff;
  for (int e = chunk * 256 + threadIdx.x; e < EDGES; e += CHUNKS * 256) {
    uint32_t n = (uint32_t)(bs * EDGES + e);
    double val = (double)lg[e] + gumbel_val(n);
    if (val > best) { best = val; bi = e; }
  }
  __shared__ double sv[256];
  __shared__ int si[256];
  sv[threadIdx.x] = best; si[threadIdx.x] = bi;
  __syncthreads();
  for (int off = 128; off; off >>= 1) {
    if (threadIdx.x < off) {
      double ov = sv[threadIdx.x + off]; int oi = si[threadIdx.x + off];
      if (ov > sv[threadIdx.x] ||
          (ov == sv[threadIdx.x] && oi < si[threadIdx.x])) {
        sv[threadIdx.x] = ov; si[threadIdx.x] = oi;
      }
    }
    __syncthreads();
  }
  if (threadIdx.x == 0) { bestval[blockIdx.x] = sv[0]; bestidx[blockIdx.x] = si[0]; }
}

// ---------------- gumbel argmax, stage 2: winner -> adj ----------------------
__global__ __launch_bounds__(64) void select_kernel(
    const double* __restrict__ bestval, const int* __restrict__ bestidx,
    const int2* __restrict__ map, float* __restrict__ adj) {
  const int bs = blockIdx.x;
  const int lane = threadIdx.x;
  double v = -1e300; int idx = 0x7fffffff;
  if (lane < CHUNKS) { v = bestval[bs * CHUNKS + lane]; idx = bestidx[bs * CHUNKS + lane]; }
#pragma unroll
  for (int off = 32; off; off >>= 1) {
    double ov = __shfl_xor(v, off, 64);
    int oi = __shfl_xor(idx, off, 64);
    if (ov > v || (ov == v && oi < idx)) { v = ov; idx = oi; }
  }
  if (lane == 0) {
    int b = bs / NSAMP;
    int2 ss = map[idx];
    adj[((b * NNODES) + ss.x) * NNODES + ss.y] = 1.0f;
  }
}

extern "C" void kernel_launch(void* const* d_in, const int* in_sizes, int n_in,
                              void* d_out, int out_size, void* d_ws, size_t ws_size,
                              hipStream_t stream) {
  const float* nodes = (const float*)d_in[0];
  const float* W1  = (const float*)d_in[1];
  const float* b1  = (const float*)d_in[2];
  const float* g1  = (const float*)d_in[3];
  const float* be1 = (const float*)d_in[4];
  const float* W2  = (const float*)d_in[5];
  const float* b2  = (const float*)d_in[6];
  const float* g2  = (const float*)d_in[7];
  const float* be2 = (const float*)d_in[8];
  const float* W3  = (const float*)d_in[9];
  const float* b3  = (const float*)d_in[10];
  float* adj = (float*)d_out;

  char* ws = (char*)d_ws;
  float* P       = (float*)(ws);                       // 1 MB  [2048][128]
  float* Q       = (float*)(ws + (1 << 20));           // 1 MB
  int2*  map     = (int2*) (ws + (2 << 20));           // 783 KB
  float* logits  = (float*)(ws + (3 << 20));           // 1.57 MB
  float* GT      = (float*)(ws + (5 << 20));           // 64 KB [n][k]
  float* SG      = (float*)(ws + (5 << 20) + 65536);
  float* SB      = (float*)(ws + (5 << 20) + 66048);
  float* GW3     = (float*)(ws + (5 << 20) + 66560);
  float* SC      = (float*)(ws + (5 << 20) + 67072);
  double* bestval = (double*)(ws + (5 << 20) + 131072);  // 800*8
  int*    bestidx = (int*)   (ws + (5 << 20) + 137472);  // 800*4

  hipMemsetAsync(adj, 0, (size_t)out_size * sizeof(float), stream);
  pq_kernel<<<(BATCH * NNODES) / 8, 256, 0, stream>>>(nodes, W1, b1, P, Q);
  map_kernel<<<(EDGES + 255) / 256, 256, 0, stream>>>(map);
  prep_kernel<<<1, 256, 0, stream>>>(W2, g1, be1, b2, g2, be2, W3, b3,
                                     GT, SG, SB, GW3, SC);
  // 765 blocks x 4 waves x 2 tiles = 6120 = NWT exactly (perfect balance)
  mlp_kernel<<<765, 256, 0, stream>>>(P, Q, map, GT, SG, SB, GW3, SC, logits);
  gumbel_kernel<<<20 * CHUNKS, 256, 0, stream>>>(logits, bestval, bestidx);
  select_kernel<<<20, 64, 0, stream>>>(bestval, bestidx, map, adj);
}

// Round 6
// 422.522 us; speedup vs baseline: 2.2425x; 1.1303x over previous
//
#include <hip/hip_runtime.h>
#include <stdint.h>

#define FEAT 128
#define NNODES 512
#define BATCH 4
#define EDGES 97920              // sum_{r=257}^{511} r ; 64 | EDGES
#define BE (BATCH*EDGES)         // 391680
#define NSAMP 5
#define BASE_OFF 32896           // 256*257/2
#define CHUNKS 40                // gumbel blocks per (b,s)
#define NWT (BE/64)              // 6120 wave-tiles (64 edges per wave)
#define MLP_GRID 510             // 510 blocks x 4 waves x 3 tiles = 6120 exactly

// ---------------- threefry2x32 (exact JAX core, key=[0,42]) ------------------
__device__ __forceinline__ void threefry2x32(uint32_t k0, uint32_t k1,
                                             uint32_t& x0, uint32_t& x1) {
  uint32_t k2 = k0 ^ k1 ^ 0x1BD11BDAu;
  x0 += k0; x1 += k1;
#define RR(r) { x0 += x1; x1 = (x1 << (r)) | (x1 >> (32 - (r))); x1 ^= x0; }
  RR(13) RR(15) RR(26) RR(6)   x0 += k1; x1 += k2 + 1u;
  RR(17) RR(29) RR(16) RR(24)  x0 += k2; x1 += k0 + 2u;
  RR(13) RR(15) RR(26) RR(6)   x0 += k0; x1 += k1 + 3u;
  RR(17) RR(29) RR(16) RR(24)  x0 += k1; x1 += k2 + 4u;
  RR(13) RR(15) RR(26) RR(6)   x0 += k2; x1 += k0 + 5u;
#undef RR
}

// partitionable threefry gumbel (verified passing rounds 2-5) — do not change
__device__ __forceinline__ double gumbel_val(uint32_t n) {
  uint32_t x0 = 0u, x1 = n;
  threefry2x32(0u, 42u, x0, x1);
  uint32_t bits = x0 ^ x1;
  uint32_t fb = (bits >> 9) | 0x3f800000u;
  float f = __uint_as_float(fb) - 1.0f;
  float u = fmaxf(f, 1.1754943508222875e-38f);
  return -log(-log((double)u));
}

// ---------------- kernel A: P = nodes @ W1_top + b1, Q = nodes @ W1_bot ------
__global__ __launch_bounds__(256) void pq_kernel(
    const float* __restrict__ nodes, const float* __restrict__ W1,
    const float* __restrict__ b1, float* __restrict__ P, float* __restrict__ Q) {
  __shared__ float snode[8][FEAT];
  const int row0 = blockIdx.x * 8;
  const int tid = threadIdx.x;
  for (int i = tid; i < 8 * FEAT; i += 256)
    snode[i >> 7][i & 127] = nodes[row0 * FEAT + i];
  __syncthreads();
  const int j = tid & 127;
  const int half = tid >> 7;                   // 0 -> P, 1 -> Q
  const float* w = W1 + half * FEAT * FEAT + j;
  float acc[8] = {0, 0, 0, 0, 0, 0, 0, 0};
  for (int k = 0; k < FEAT; ++k) {
    float wv = w[k * FEAT];
#pragma unroll
    for (int m = 0; m < 8; ++m) acc[m] += snode[m][k] * wv;
  }
  const float bv = half ? 0.0f : b1[j];
  float* out = half ? Q : P;
#pragma unroll
  for (int m = 0; m < 8; ++m) out[(row0 + m) * FEAT + j] = acc[m] + bv;
}

// ---------------- edge index -> (sink, src) ----------------------------------
__global__ __launch_bounds__(256) void map_kernel(int2* __restrict__ map) {
  int e = blockIdx.x * blockDim.x + threadIdx.x;
  if (e >= EDGES) return;
  double x = (double)(e + BASE_OFF);
  int s = (int)((1.0 + sqrt(1.0 + 8.0 * x)) * 0.5);
  while ((long long)s * (s - 1) / 2 - BASE_OFF > e) --s;
  while ((long long)(s + 1) * s / 2 - BASE_OFF <= e) ++s;
  int src = e - (int)((long long)s * (s - 1) / 2 - BASE_OFF);
  map[e] = make_int2(s, src);
}

// ---------------- prep: GT[n][k] = g1[k]*W2[k][n], SG, SB, GW3, SC -----------
__global__ __launch_bounds__(256) void prep_kernel(
    const float* __restrict__ W2, const float* __restrict__ g1,
    const float* __restrict__ be1, const float* __restrict__ b2,
    const float* __restrict__ g2, const float* __restrict__ be2,
    const float* __restrict__ W3, const float* __restrict__ b3,
    float* __restrict__ GT, float* __restrict__ SG, float* __restrict__ SB,
    float* __restrict__ GW3, float* __restrict__ SC) {
  const int tid = threadIdx.x;
  for (int idx = tid; idx < FEAT * FEAT; idx += 256) {
    const int n = idx >> 7, k = idx & 127;
    GT[idx] = g1[k] * W2[k * FEAT + n];
  }
  if (tid < FEAT) {
    float sg = 0.f, sb = 0.f;
    for (int k = 0; k < FEAT; ++k) {
      float w = W2[k * FEAT + tid];
      sg = fmaf(g1[k], w, sg);
      sb = fmaf(be1[k], w, sb);
    }
    SG[tid] = sg;
    SB[tid] = sb + b2[tid];
    GW3[tid] = g2[tid] * W3[tid];
  }
  __syncthreads();
  if (tid == 0) {
    float a = 0.f, c = 0.f;
    for (int n = 0; n < FEAT; ++n) { a += GW3[n]; c = fmaf(be2[n], W3[n], c); }
    SC[0] = a; SC[1] = c + b3[0];
  }
}

// ---------------- main MLP kernel ---------------------------------------------
// lane = edge; h[128] register-resident. Block-uniform control flow (fixed
// 3-iteration loop) so GT column loads are provably uniform -> s_load +
// v_fmac_f32 with SGPR operand. No LDS, no shuffles, no barriers.
__global__ __launch_bounds__(256, 2) void mlp_kernel(
    const float* __restrict__ P, const float* __restrict__ Q,
    const int2* __restrict__ map, const float* __restrict__ GT,
    const float* __restrict__ SG, const float* __restrict__ SB,
    const float* __restrict__ GW3, const float* __restrict__ SC,
    float* __restrict__ logits) {
  const int lane = threadIdx.x & 63;
  const int wave = threadIdx.x >> 6;
  const float sgw3 = SC[0], cb = SC[1];

#pragma unroll 1
  for (int it = 0; it < 3; ++it) {           // compile-time trip count: uniform
    const int wt = blockIdx.x * 12 + it * 4 + wave;   // < 6120 always
    const int g0 = wt * 64;
    const int b = g0 / EDGES;            // 64 | EDGES: tile never crosses batch
    const int e = (g0 - b * EDGES) + lane;
    const int2 ss = map[e];
    const float4* prow = (const float4*)(P + (((b << 9) + ss.x) << 7));
    const float4* qrow = (const float4*)(Q + (((b << 9) + ss.y) << 7));

    // ---- stage 1: h = relu(P[sink] + Q[src]) into registers; LN1 stats ----
    float4 h4[32];
    float s1 = 0.f, q1 = 0.f;
#pragma unroll
    for (int i = 0; i < 32; ++i) {
      const float4 pv = prow[i];
      const float4 qv = qrow[i];
      float4 h;
      h.x = fmaxf(pv.x + qv.x, 0.f);
      h.y = fmaxf(pv.y + qv.y, 0.f);
      h.z = fmaxf(pv.z + qv.z, 0.f);
      h.w = fmaxf(pv.w + qv.w, 0.f);
      h4[i] = h;
      s1 += (h.x + h.y) + (h.z + h.w);
      q1 = fmaf(h.x, h.x, q1); q1 = fmaf(h.y, h.y, q1);
      q1 = fmaf(h.z, h.z, q1); q1 = fmaf(h.w, h.w, q1);
    }
    const float mu1 = s1 * (1.0f / 128.0f);
    const float var1 = fmaxf(q1 * (1.0f / 128.0f) - mu1 * mu1, 0.0f);
    const float rs1 = rsqrtf(var1 + 1e-5f);

    // ---- stage 2: per n, S = h . GT[n] (GT col via s_load); fold LN1; LN2 ----
    float s2 = 0.f, q2 = 0.f, t = 0.f;
#pragma unroll 1
    for (int n = 0; n < FEAT; ++n) {
      const float* gc = GT + (n << 7);        // uniform address -> SGPRs
      float2 acA = make_float2(0.f, 0.f);
      float2 acB = make_float2(0.f, 0.f);
#pragma unroll
      for (int i = 0; i < 32; ++i) {
        acA.x = fmaf(h4[i].x, gc[4 * i + 0], acA.x);
        acA.y = fmaf(h4[i].y, gc[4 * i + 1], acA.y);
        acB.x = fmaf(h4[i].z, gc[4 * i + 2], acB.x);
        acB.y = fmaf(h4[i].w, gc[4 * i + 3], acB.y);
      }
      const float S = (acA.x + acA.y) + (acB.x + acB.y);
      const float h2 = fmaxf(rs1 * (S - mu1 * SG[n]) + SB[n], 0.f);
      s2 += h2;
      q2 = fmaf(h2, h2, q2);
      t = fmaf(h2, GW3[n], t);
    }
    const float mu2 = s2 * (1.0f / 128.0f);
    const float var2 = fmaxf(q2 * (1.0f / 128.0f) - mu2 * mu2, 0.0f);
    const float rs2 = rsqrtf(var2 + 1e-5f);
    logits[g0 + lane] = rs2 * (t - mu2 * sgw3) + cb;
  }
}

// ---------------- gumbel argmax, stage 1: per-(bs,chunk) best ----------------
__global__ __launch_bounds__(256) void gumbel_kernel(
    const float* __restrict__ logits, double* __restrict__ bestval,
    int* __restrict__ bestidx) {
  const int bs = blockIdx.x / CHUNKS;     // b*5 + s
  const int chunk = blockIdx.x % CHUNKS;
  const int b = bs / NSAMP;
  const float* lg = logits + b * EDGES;
  double best = -1e300; int bi = 0x7fffffff;
  for (int e = chunk * 256 + threadIdx.x; e < EDGES; e += CHUNKS * 256) {
    uint32_t n = (uint32_t)(bs * EDGES + e);
    double val = (double)lg[e] + gumbel_val(n);
    if (val > best) { best = val; bi = e; }
  }
  __shared__ double sv[256];
  __shared__ int si[256];
  sv[threadIdx.x] = best; si[threadIdx.x] = bi;
  __syncthreads();
  for (int off = 128; off; off >>= 1) {
    if (threadIdx.x < off) {
      double ov = sv[threadIdx.x + off]; int oi = si[threadIdx.x + off];
      if (ov > sv[threadIdx.x] ||
          (ov == sv[threadIdx.x] && oi < si[threadIdx.x])) {
        sv[threadIdx.x] = ov; si[threadIdx.x] = oi;
      }
    }
    __syncthreads();
  }
  if (threadIdx.x == 0) { bestval[blockIdx.x] = sv[0]; bestidx[blockIdx.x] = si[0]; }
}

// ---------------- gumbel argmax, stage 2: winner -> adj ----------------------
__global__ __launch_bounds__(64) void select_kernel(
    const double* __restrict__ bestval, const int* __restrict__ bestidx,
    const int2* __restrict__ map, float* __restrict__ adj) {
  const int bs = blockIdx.x;
  const int lane = threadIdx.x;
  double v = -1e300; int idx = 0x7fffffff;
  if (lane < CHUNKS) { v = bestval[bs * CHUNKS + lane]; idx = bestidx[bs * CHUNKS + lane]; }
#pragma unroll
  for (int off = 32; off; off >>= 1) {
    double ov = __shfl_xor(v, off, 64);
    int oi = __shfl_xor(idx, off, 64);
    if (ov > v || (ov == v && oi < idx)) { v = ov; idx = oi; }
  }
  if (lane == 0) {
    int b = bs / NSAMP;
    int2 ss = map[idx];
    adj[((b * NNODES) + ss.x) * NNODES + ss.y] = 1.0f;
  }
}

extern "C" void kernel_launch(void* const* d_in, const int* in_sizes, int n_in,
                              void* d_out, int out_size, void* d_ws, size_t ws_size,
                              hipStream_t stream) {
  const float* nodes = (const float*)d_in[0];
  const float* W1  = (const float*)d_in[1];
  const float* b1  = (const float*)d_in[2];
  const float* g1  = (const float*)d_in[3];
  const float* be1 = (const float*)d_in[4];
  const float* W2  = (const float*)d_in[5];
  const float* b2  = (const float*)d_in[6];
  const float* g2  = (const float*)d_in[7];
  const float* be2 = (const float*)d_in[8];
  const float* W3  = (const float*)d_in[9];
  const float* b3  = (const float*)d_in[10];
  float* adj = (float*)d_out;

  char* ws = (char*)d_ws;
  float* P       = (float*)(ws);                       // 1 MB  [2048][128]
  float* Q       = (float*)(ws + (1 << 20));           // 1 MB
  int2*  map     = (int2*) (ws + (2 << 20));           // 783 KB
  float* logits  = (float*)(ws + (3 << 20));           // 1.57 MB
  float* GT      = (float*)(ws + (5 << 20));           // 64 KB [n][k]
  float* SG      = (float*)(ws + (5 << 20) + 65536);
  float* SB      = (float*)(ws + (5 << 20) + 66048);
  float* GW3     = (float*)(ws + (5 << 20) + 66560);
  float* SC      = (float*)(ws + (5 << 20) + 67072);
  double* bestval = (double*)(ws + (5 << 20) + 131072);  // 800*8
  int*    bestidx = (int*)   (ws + (5 << 20) + 137472);  // 800*4

  hipMemsetAsync(adj, 0, (size_t)out_size * sizeof(float), stream);
  pq_kernel<<<(BATCH * NNODES) / 8, 256, 0, stream>>>(nodes, W1, b1, P, Q);
  map_kernel<<<(EDGES + 255) / 256, 256, 0, stream>>>(map);
  prep_kernel<<<1, 256, 0, stream>>>(W2, g1, be1, b2, g2, be2, W3, b3,
                                     GT, SG, SB, GW3, SC);
  mlp_kernel<<<MLP_GRID, 256, 0, stream>>>(P, Q, map, GT, SG, SB, GW3, SC, logits);
  gumbel_kernel<<<20 * CHUNKS, 256, 0, stream>>>(logits, bestval, bestidx);
  select_kernel<<<20, 64, 0, stream>>>(bestval, bestidx, map, adj);
}